// Round 2
// baseline (4661.997 us; speedup 1.0000x reference)
//
#include <hip/hip_runtime.h>
#include <hip/hip_bf16.h>
#include <stdint.h>

#define N_NODES 100000
#define N_EDGES 1600000
#define IN_DIM 128
#define HEADS 4
#define HID 32
#define HC 128
#define NUM_CLASSES 349
#define NUM_LAYERS 2
#define BN_EPS 1e-5f
#define NEG_SLOPE 0.2f
#define NCAT 264   // [xs(128) | s_src(4) | s_dst(4) | xlin(128)]

using bf16 = __hip_bfloat16;

__device__ __forceinline__ float b2f(bf16 v) { return __bfloat162float(v); }

// -------------------------------------------------- runtime dtype detection
// If the float tensors are stored as fp32, the low 16 bits of each 32-bit
// word are random mantissa bits -> decoded as bf16 they have wild exponents.
// If stored as bf16, the low 16 bits are a real bf16 value of N(0,1) data
// -> exponent in ~[117,130]. flag=1 => buffers are fp32.
__global__ void detect_dtype(const uint32_t* __restrict__ xw, int* __restrict__ flag) {
    if (threadIdx.x != 0 || blockIdx.x != 0) return;
    int insane = 0;
    for (int i = 0; i < 256; i++) {
        uint32_t lo = xw[i] & 0xffffu;
        uint32_t e = (lo >> 7) & 0xffu;
        if (lo != 0u && (e < 100u || e > 150u)) insane++;
    }
    *flag = (insane > 64) ? 1 : 0;
}

// ------------------------------------------- dtype-flexible convert to fp32
__global__ void cvt_f32(const void* __restrict__ in, float* __restrict__ out,
                        int n, const int* __restrict__ flag) {
    bool isf32 = (*flag != 0);
    int i = blockIdx.x * blockDim.x + threadIdx.x;
    int stride = gridDim.x * blockDim.x;
    for (; i < n; i += stride)
        out[i] = isf32 ? ((const float*)in)[i] : b2f(((const bf16*)in)[i]);
}

// ------------------------------------------------------- build fused B matrix
// B_cat [128 x 264] = [W_src | wtilde_src | wtilde_dst | lin_W]  (fp32 in/out)
__global__ void build_bcat(const float* __restrict__ Wsrc, const float* __restrict__ Wdst,
                           const float* __restrict__ asrc, const float* __restrict__ adst,
                           const float* __restrict__ linW, float* __restrict__ B) {
    int idx = blockIdx.x * blockDim.x + threadIdx.x;
    if (idx >= IN_DIM * NCAT) return;
    int k = idx / NCAT, j = idx - k * NCAT;
    float v;
    if (j < 128) {
        v = Wsrc[k * HC + j];
    } else if (j < 132) {
        int h = j - 128; float s = 0.f;
        for (int c = 0; c < HID; c++) s += Wsrc[k * HC + h * HID + c] * asrc[h * HID + c];
        v = s;
    } else if (j < 136) {
        int h = j - 132; float s = 0.f;
        for (int c = 0; c < HID; c++) s += Wdst[k * HC + h * HID + c] * adst[h * HID + c];
        v = s;
    } else {
        v = linW[k * HC + (j - 136)];
    }
    B[idx] = v;
}

// ---------------------------------------------------------------- simple GEMM
// C[M,N] = A[M,K] @ B[K,N], fp32 in, bf16 out (proj).
__global__ void gemm_proj(const float* __restrict__ A, const float* __restrict__ B,
                          bf16* __restrict__ C, int M, int N, int K) {
    __shared__ float As[16][17];
    __shared__ float Bs[16][17];
    int tx = threadIdx.x, ty = threadIdx.y;
    int row = blockIdx.y * 16 + ty;
    int col = blockIdx.x * 16 + tx;
    float acc = 0.f;
    for (int k0 = 0; k0 < K; k0 += 16) {
        As[ty][tx] = (row < M) ? A[row * K + k0 + tx] : 0.f;
        Bs[ty][tx] = (col < N) ? B[(k0 + ty) * N + col] : 0.f;
        __syncthreads();
#pragma unroll
        for (int kk = 0; kk < 16; kk++) acc += As[ty][kk] * Bs[kk][tx];
        __syncthreads();
    }
    if (row < M && col < N) C[row * N + col] = __float2bfloat16(acc);
}

// Final GEMM: fp32 in, +bias, dtype-flag store.
__global__ void gemm_out(const float* __restrict__ A, const float* __restrict__ B,
                         const float* __restrict__ bias, void* __restrict__ C,
                         int M, int N, int K, const int* __restrict__ flag) {
    __shared__ float As[16][17];
    __shared__ float Bs[16][17];
    int tx = threadIdx.x, ty = threadIdx.y;
    int row = blockIdx.y * 16 + ty;
    int col = blockIdx.x * 16 + tx;
    float acc = 0.f;
    for (int k0 = 0; k0 < K; k0 += 16) {
        As[ty][tx] = (row < M) ? A[row * K + k0 + tx] : 0.f;
        Bs[ty][tx] = (col < N) ? B[(k0 + ty) * N + col] : 0.f;
        __syncthreads();
#pragma unroll
        for (int kk = 0; kk < 16; kk++) acc += As[ty][kk] * Bs[kk][tx];
        __syncthreads();
    }
    if (row < M && col < N) {
        acc += bias[col];
        if (*flag) ((float*)C)[row * N + col] = acc;
        else       ((bf16*)C)[row * N + col] = __float2bfloat16(acc);
    }
}

// ------------------------------------------------------------ edge softmax denom
__global__ void edge_denom(const int* __restrict__ src, const int* __restrict__ dst,
                           const bf16* __restrict__ proj, float* __restrict__ denom) {
    int tid = blockIdx.x * blockDim.x + threadIdx.x;
    if (tid >= N_EDGES * HEADS) return;
    int e = tid >> 2, h = tid & 3;
    int s = src[e], d = dst[e];
    float sc = b2f(proj[s * NCAT + 128 + h]) + b2f(proj[d * NCAT + 132 + h]);
    sc = sc > 0.f ? sc : NEG_SLOPE * sc;
    atomicAdd(&denom[d * HEADS + h], __expf(sc));
}

// ------------------------------------------------------------ edge message scatter
// 64 lanes per edge, 2 channels per lane
__global__ void edge_msg(const int* __restrict__ src, const int* __restrict__ dst,
                         const bf16* __restrict__ proj, const float* __restrict__ denom,
                         float* __restrict__ acc) {
    int tid = blockIdx.x * blockDim.x + threadIdx.x;
    int e = tid >> 6;
    if (e >= N_EDGES) return;
    int lane = tid & 63;
    int c0 = lane * 2;
    int h = c0 >> 5;
    int s = src[e], d = dst[e];
    float sc = b2f(proj[s * NCAT + 128 + h]) + b2f(proj[d * NCAT + 132 + h]);
    sc = sc > 0.f ? sc : NEG_SLOPE * sc;
    float alpha = __expf(sc) / (denom[d * HEADS + h] + 1e-16f);
    const __hip_bfloat162 xv = *reinterpret_cast<const __hip_bfloat162*>(&proj[s * NCAT + c0]);
    atomicAdd(&acc[d * HC + c0],     b2f(xv.x) * alpha);
    atomicAdd(&acc[d * HC + c0 + 1], b2f(xv.y) * alpha);
}

// ------------------------------------------ h = acc + bias + skip; BN partial sums
__global__ void post_bn(float* __restrict__ acc, const bf16* __restrict__ proj,
                        const float* __restrict__ cbias, const float* __restrict__ lbias,
                        float* __restrict__ bnsum, float* __restrict__ bnsq) {
    int c = threadIdx.x & 127;
    int half = threadIdx.x >> 7;  // 0/1
    int r0 = blockIdx.x * 128;
    int rend = r0 + 128; if (rend > N_NODES) rend = N_NODES;
    float bias = cbias[c] + lbias[c];
    float s1 = 0.f, s2 = 0.f;
    for (int r = r0 + half; r < rend; r += 2) {
        float v = acc[r * HC + c] + b2f(proj[r * NCAT + 136 + c]) + bias;
        acc[r * HC + c] = v;
        s1 += v; s2 += v * v;
    }
    atomicAdd(&bnsum[c], s1);
    atomicAdd(&bnsq[c], s2);
}

// ------------------------------------------------------- BN normalize + ReLU
__global__ void bn_apply(const float* __restrict__ h, float* __restrict__ xout,
                         const float* __restrict__ gamma, const float* __restrict__ beta,
                         const float* __restrict__ bnsum, const float* __restrict__ bnsq) {
    int idx = blockIdx.x * blockDim.x + threadIdx.x;
    if (idx >= N_NODES * HC) return;
    int c = idx & 127;
    const float invN = 1.f / (float)N_NODES;
    float mu = bnsum[c] * invN;
    float var = bnsq[c] * invN - mu * mu;
    float v = gamma[c] * (h[idx] - mu) * rsqrtf(var + BN_EPS) + beta[c];
    xout[idx] = v > 0.f ? v : 0.f;
}

// ==========================================================================
extern "C" void kernel_launch(void* const* d_in, const int* in_sizes, int n_in,
                              void* d_out, int out_size, void* d_ws, size_t ws_size,
                              hipStream_t stream) {
    const void* x_in  = d_in[0];
    const int*  edge  = (const int*)d_in[1];
    const int* esrc = edge;
    const int* edst = edge + N_EDGES;

    // ---- d_ws layout (lean: ~105 MB) ----
    float* ws    = (float*)d_ws;
    float* xf    = ws;                                    // N*128 f32      (51.2 MB)
    bf16*  proj  = (bf16*)(xf + (size_t)N_NODES * HC);    // N*264 bf16     (52.8 MB)
    float* after = (float*)(proj + (size_t)N_NODES * NCAT);
    float* Bcat  = after;                                 // 128*264 f32
    float* bnsum = Bcat + IN_DIM * NCAT;                  // 128
    float* bnsq  = bnsum + 128;                           // 128
    int*   flag  = (int*)(bnsq + 128);                    // 1
    float* parms = (float*)(flag + 4);
    // fp32 parameter copies
    float* Wsrc_f = parms;                       // 2*128*128
    float* Wdst_f = Wsrc_f + 2 * IN_DIM * HC;    // 2*128*128
    float* asrc_f = Wdst_f + 2 * IN_DIM * HC;    // 2*128
    float* adst_f = asrc_f + 2 * HEADS * HID;    // 2*128
    float* cbias_f= adst_f + 2 * HEADS * HID;    // 2*128
    float* linW_f = cbias_f + 2 * HC;            // 2*128*128
    float* linb_f = linW_f + 2 * IN_DIM * HC;    // 2*128
    float* gamma_f= linb_f + 2 * HC;             // 2*128
    float* beta_f = gamma_f + 2 * HC;            // 2*128
    float* fcW_f  = beta_f + 2 * HC;             // 128*349
    float* fcb_f  = fcW_f + IN_DIM * NUM_CLASSES;// 349

    // ---- d_out doubles as scratch for acc+denom (dead before final GEMM) ----
    float* acc   = (float*)d_out;                         // N*128 f32 (51.2 MB)
    float* denom = acc + (size_t)N_NODES * HC;            // N*4   f32 (1.6 MB)  total 52.8 <= 69.8 MB

    detect_dtype<<<1, 64, 0, stream>>>((const uint32_t*)x_in, flag);

    // convert all float params (+x) to canonical fp32
    cvt_f32<<<1024, 256, 0, stream>>>(x_in, xf, N_NODES * HC, flag);
    cvt_f32<<<64, 256, 0, stream>>>(d_in[2], Wsrc_f, 2 * IN_DIM * HC, flag);
    cvt_f32<<<64, 256, 0, stream>>>(d_in[3], Wdst_f, 2 * IN_DIM * HC, flag);
    cvt_f32<<<1, 256, 0, stream>>>(d_in[4], asrc_f, 2 * HEADS * HID, flag);
    cvt_f32<<<1, 256, 0, stream>>>(d_in[5], adst_f, 2 * HEADS * HID, flag);
    cvt_f32<<<1, 256, 0, stream>>>(d_in[6], cbias_f, 2 * HC, flag);
    cvt_f32<<<64, 256, 0, stream>>>(d_in[7], linW_f, 2 * IN_DIM * HC, flag);
    cvt_f32<<<1, 256, 0, stream>>>(d_in[8], linb_f, 2 * HC, flag);
    cvt_f32<<<1, 256, 0, stream>>>(d_in[9], gamma_f, 2 * HC, flag);
    cvt_f32<<<1, 256, 0, stream>>>(d_in[10], beta_f, 2 * HC, flag);
    cvt_f32<<<175, 256, 0, stream>>>(d_in[11], fcW_f, IN_DIM * NUM_CLASSES, flag);
    cvt_f32<<<2, 256, 0, stream>>>(d_in[12], fcb_f, NUM_CLASSES, flag);

    for (int layer = 0; layer < NUM_LAYERS; layer++) {
        const int woff = layer * IN_DIM * HC;
        const int aoff = layer * HEADS * HID;
        const int boff = layer * HC;

        build_bcat<<<(IN_DIM * NCAT + 255) / 256, 256, 0, stream>>>(
            Wsrc_f + woff, Wdst_f + woff, asrc_f + aoff, adst_f + aoff,
            linW_f + woff, Bcat);

        dim3 gb((NCAT + 15) / 16, (N_NODES + 15) / 16);
        gemm_proj<<<gb, dim3(16, 16), 0, stream>>>(xf, Bcat, proj,
                                                   N_NODES, NCAT, IN_DIM);

        hipMemsetAsync(acc, 0, (size_t)N_NODES * (HC + HEADS) * sizeof(float), stream);
        hipMemsetAsync(bnsum, 0, 256 * sizeof(float), stream);  // bnsum+bnsq contiguous

        edge_denom<<<(N_EDGES * HEADS + 255) / 256, 256, 0, stream>>>(esrc, edst, proj, denom);
        edge_msg<<<(N_EDGES * 64) / 256, 256, 0, stream>>>(esrc, edst, proj, denom, acc);

        post_bn<<<(N_NODES + 127) / 128, 256, 0, stream>>>(
            acc, proj, cbias_f + boff, linb_f + boff, bnsum, bnsq);
        bn_apply<<<(N_NODES * HC + 255) / 256, 256, 0, stream>>>(
            acc, xf, gamma_f + boff, beta_f + boff, bnsum, bnsq);
    }

    dim3 gf((NUM_CLASSES + 15) / 16, (N_NODES + 15) / 16);
    gemm_out<<<gf, dim3(16, 16), 0, stream>>>(xf, fcW_f, fcb_f, d_out,
                                              N_NODES, NUM_CLASSES, IN_DIM, flag);
}

// Round 3
// 2923.374 us; speedup vs baseline: 1.5947x; 1.5947x over previous
//
#include <hip/hip_runtime.h>
#include <hip/hip_bf16.h>
#include <stdint.h>

#define N_NODES 100000
#define N_EDGES 1600000
#define IN_DIM 128
#define HEADS 4
#define HID 32
#define HC 128
#define NUM_CLASSES 349
#define NUM_LAYERS 2
#define BN_EPS 1e-5f
#define NEG_SLOPE 0.2f
#define NCAT 264   // [xs(128) | s_src(4) | s_dst(4) | xlin(128)]

#define SCAN_CHUNK 1024
#define SCAN_BLOCKS ((N_NODES + SCAN_CHUNK - 1) / SCAN_CHUNK)  // 98

using bf16 = __hip_bfloat16;

__device__ __forceinline__ float b2f(bf16 v) { return __bfloat162float(v); }

// -------------------------------------------------- runtime dtype detection
__global__ void detect_dtype(const uint32_t* __restrict__ xw, int* __restrict__ flag) {
    if (threadIdx.x != 0 || blockIdx.x != 0) return;
    int insane = 0;
    for (int i = 0; i < 256; i++) {
        uint32_t lo = xw[i] & 0xffffu;
        uint32_t e = (lo >> 7) & 0xffu;
        if (lo != 0u && (e < 100u || e > 150u)) insane++;
    }
    *flag = (insane > 64) ? 1 : 0;
}

// ------------------------------------------- dtype-flexible convert to fp32
__global__ void cvt_f32(const void* __restrict__ in, float* __restrict__ out,
                        int n, const int* __restrict__ flag) {
    bool isf32 = (*flag != 0);
    int i = blockIdx.x * blockDim.x + threadIdx.x;
    int stride = gridDim.x * blockDim.x;
    for (; i < n; i += stride)
        out[i] = isf32 ? ((const float*)in)[i] : b2f(((const bf16*)in)[i]);
}

// ------------------------------------------------------- build fused B matrix
__global__ void build_bcat(const float* __restrict__ Wsrc, const float* __restrict__ Wdst,
                           const float* __restrict__ asrc, const float* __restrict__ adst,
                           const float* __restrict__ linW, float* __restrict__ B) {
    int idx = blockIdx.x * blockDim.x + threadIdx.x;
    if (idx >= IN_DIM * NCAT) return;
    int k = idx / NCAT, j = idx - k * NCAT;
    float v;
    if (j < 128) {
        v = Wsrc[k * HC + j];
    } else if (j < 132) {
        int h = j - 128; float s = 0.f;
        for (int c = 0; c < HID; c++) s += Wsrc[k * HC + h * HID + c] * asrc[h * HID + c];
        v = s;
    } else if (j < 136) {
        int h = j - 132; float s = 0.f;
        for (int c = 0; c < HID; c++) s += Wdst[k * HC + h * HID + c] * adst[h * HID + c];
        v = s;
    } else {
        v = linW[k * HC + (j - 136)];
    }
    B[idx] = v;
}

// ---------------------------------------------------------------- simple GEMM
__global__ void gemm_proj(const float* __restrict__ A, const float* __restrict__ B,
                          bf16* __restrict__ C, int M, int N, int K) {
    __shared__ float As[16][17];
    __shared__ float Bs[16][17];
    int tx = threadIdx.x, ty = threadIdx.y;
    int row = blockIdx.y * 16 + ty;
    int col = blockIdx.x * 16 + tx;
    float acc = 0.f;
    for (int k0 = 0; k0 < K; k0 += 16) {
        As[ty][tx] = (row < M) ? A[row * K + k0 + tx] : 0.f;
        Bs[ty][tx] = (col < N) ? B[(k0 + ty) * N + col] : 0.f;
        __syncthreads();
#pragma unroll
        for (int kk = 0; kk < 16; kk++) acc += As[ty][kk] * Bs[kk][tx];
        __syncthreads();
    }
    if (row < M && col < N) C[row * N + col] = __float2bfloat16(acc);
}

__global__ void gemm_out(const float* __restrict__ A, const float* __restrict__ B,
                         const float* __restrict__ bias, void* __restrict__ C,
                         int M, int N, int K, const int* __restrict__ flag) {
    __shared__ float As[16][17];
    __shared__ float Bs[16][17];
    int tx = threadIdx.x, ty = threadIdx.y;
    int row = blockIdx.y * 16 + ty;
    int col = blockIdx.x * 16 + tx;
    float acc = 0.f;
    for (int k0 = 0; k0 < K; k0 += 16) {
        As[ty][tx] = (row < M) ? A[row * K + k0 + tx] : 0.f;
        Bs[ty][tx] = (col < N) ? B[(k0 + ty) * N + col] : 0.f;
        __syncthreads();
#pragma unroll
        for (int kk = 0; kk < 16; kk++) acc += As[ty][kk] * Bs[kk][tx];
        __syncthreads();
    }
    if (row < M && col < N) {
        acc += bias[col];
        if (*flag) ((float*)C)[row * N + col] = acc;
        else       ((bf16*)C)[row * N + col] = __float2bfloat16(acc);
    }
}

// ================================ CSR build ================================
__global__ void hist_dst(const int* __restrict__ dst, int* __restrict__ counts) {
    int e = blockIdx.x * blockDim.x + threadIdx.x;
    if (e < N_EDGES) atomicAdd(&counts[dst[e]], 1);
}

__global__ void scan_partial(const int* __restrict__ counts, int* __restrict__ bsum) {
    __shared__ int red[256];
    int t = threadIdx.x;
    int base = blockIdx.x * SCAN_CHUNK + t * 4;
    int s = 0;
#pragma unroll
    for (int j = 0; j < 4; j++) {
        int idx = base + j;
        if (idx < N_NODES) s += counts[idx];
    }
    red[t] = s;
    __syncthreads();
    for (int off = 128; off > 0; off >>= 1) {
        if (t < off) red[t] += red[t + off];
        __syncthreads();
    }
    if (t == 0) bsum[blockIdx.x] = red[0];
}

__global__ void scan_bsums(int* __restrict__ bsum) {
    if (threadIdx.x != 0 || blockIdx.x != 0) return;
    int run = 0;
    for (int i = 0; i < SCAN_BLOCKS; i++) {
        int v = bsum[i];
        bsum[i] = run;
        run += v;
    }
}

__global__ void scan_final(const int* __restrict__ counts, const int* __restrict__ bsum,
                           int* __restrict__ offsets) {
    __shared__ int ts[256];
    int t = threadIdx.x;
    int base = blockIdx.x * SCAN_CHUNK + t * 4;
    int c[4];
    int mysum = 0;
#pragma unroll
    for (int j = 0; j < 4; j++) {
        int idx = base + j;
        c[j] = (idx < N_NODES) ? counts[idx] : 0;
        mysum += c[j];
    }
    ts[t] = mysum;
    __syncthreads();
    // Hillis-Steele inclusive scan over 256 entries
    for (int off = 1; off < 256; off <<= 1) {
        int v = (t >= off) ? ts[t - off] : 0;
        __syncthreads();
        ts[t] += v;
        __syncthreads();
    }
    int run = bsum[blockIdx.x] + ts[t] - mysum;  // exclusive prefix for this thread
#pragma unroll
    for (int j = 0; j < 4; j++) {
        int idx = base + j;
        if (idx < N_NODES) {
            offsets[idx] = run;
            run += c[j];
            if (idx == N_NODES - 1) offsets[N_NODES] = run;
        }
    }
}

__global__ void copy_i32(const int* __restrict__ in, int* __restrict__ out, int n) {
    int i = blockIdx.x * blockDim.x + threadIdx.x;
    if (i < n) out[i] = in[i];
}

__global__ void scatter_edges(const int* __restrict__ dst, int* __restrict__ cursor,
                              int* __restrict__ eids) {
    int e = blockIdx.x * blockDim.x + threadIdx.x;
    if (e >= N_EDGES) return;
    int pos = atomicAdd(&cursor[dst[e]], 1);
    eids[pos] = e;
}

// ================================ GAT gather ================================
// one wave per destination node; 2 channels per lane; two passes over segment
__global__ void gat_gather(const int* __restrict__ eids,
                           const int* __restrict__ offsets,
                           const int* __restrict__ src,
                           const bf16* __restrict__ proj,
                           float* __restrict__ acc) {
    int n = blockIdx.x * 4 + (threadIdx.x >> 6);
    int lane = threadIdx.x & 63;
    int c0 = lane * 2;
    int h = c0 >> 5;
    int beg = offsets[n], end = offsets[n + 1];
    float s_dst = b2f(proj[(size_t)n * NCAT + 132 + h]);
    // pass 1: softmax denominator (per-head, redundant across 16 lanes — broadcast loads)
    float denom = 0.f;
    for (int i = beg; i < end; i++) {
        int s = src[eids[i]];
        float sc = b2f(proj[(size_t)s * NCAT + 128 + h]) + s_dst;
        sc = sc > 0.f ? sc : NEG_SLOPE * sc;
        denom += __expf(sc);
    }
    float rdenom = 1.f / (denom + 1e-16f);
    // pass 2: weighted message accumulate
    float a0 = 0.f, a1 = 0.f;
    for (int i = beg; i < end; i++) {
        int s = src[eids[i]];
        size_t rb = (size_t)s * NCAT;
        float sc = b2f(proj[rb + 128 + h]) + s_dst;
        sc = sc > 0.f ? sc : NEG_SLOPE * sc;
        float alpha = __expf(sc) * rdenom;
        __hip_bfloat162 xv = *reinterpret_cast<const __hip_bfloat162*>(&proj[rb + c0]);
        a0 += b2f(xv.x) * alpha;
        a1 += b2f(xv.y) * alpha;
    }
    acc[(size_t)n * HC + c0]     = a0;
    acc[(size_t)n * HC + c0 + 1] = a1;
}

// ------------------------------------------ h = acc + bias + skip; BN partial sums
__global__ void post_bn(float* __restrict__ acc, const bf16* __restrict__ proj,
                        const float* __restrict__ cbias, const float* __restrict__ lbias,
                        float* __restrict__ bnsum, float* __restrict__ bnsq) {
    int c = threadIdx.x & 127;
    int half = threadIdx.x >> 7;  // 0/1
    int r0 = blockIdx.x * 128;
    int rend = r0 + 128; if (rend > N_NODES) rend = N_NODES;
    float bias = cbias[c] + lbias[c];
    float s1 = 0.f, s2 = 0.f;
    for (int r = r0 + half; r < rend; r += 2) {
        float v = acc[r * HC + c] + b2f(proj[(size_t)r * NCAT + 136 + c]) + bias;
        acc[r * HC + c] = v;
        s1 += v; s2 += v * v;
    }
    atomicAdd(&bnsum[c], s1);
    atomicAdd(&bnsq[c], s2);
}

// ------------------------------------------------------- BN normalize + ReLU
__global__ void bn_apply(const float* __restrict__ h, float* __restrict__ xout,
                         const float* __restrict__ gamma, const float* __restrict__ beta,
                         const float* __restrict__ bnsum, const float* __restrict__ bnsq) {
    int idx = blockIdx.x * blockDim.x + threadIdx.x;
    if (idx >= N_NODES * HC) return;
    int c = idx & 127;
    const float invN = 1.f / (float)N_NODES;
    float mu = bnsum[c] * invN;
    float var = bnsq[c] * invN - mu * mu;
    float v = gamma[c] * (h[idx] - mu) * rsqrtf(var + BN_EPS) + beta[c];
    xout[idx] = v > 0.f ? v : 0.f;
}

// ==========================================================================
extern "C" void kernel_launch(void* const* d_in, const int* in_sizes, int n_in,
                              void* d_out, int out_size, void* d_ws, size_t ws_size,
                              hipStream_t stream) {
    const void* x_in  = d_in[0];
    const int*  edge  = (const int*)d_in[1];
    const int* esrc = edge;
    const int* edst = edge + N_EDGES;

    // ---- d_ws layout ----
    float* ws    = (float*)d_ws;
    float* xf    = ws;                                    // N*128 f32      (51.2 MB)
    bf16*  proj  = (bf16*)(xf + (size_t)N_NODES * HC);    // N*264 bf16     (52.8 MB)
    float* after = (float*)(proj + (size_t)N_NODES * NCAT);
    float* Bcat  = after;                                 // 128*264 f32
    float* bnsum = Bcat + IN_DIM * NCAT;                  // 128
    float* bnsq  = bnsum + 128;                           // 128
    int*   flag  = (int*)(bnsq + 128);                    // 1 (+pad)
    int*   bsum  = flag + 4;                              // SCAN_BLOCKS (98)
    float* parms = (float*)(bsum + SCAN_BLOCKS + 2);
    float* Wsrc_f = parms;                       // 2*128*128
    float* Wdst_f = Wsrc_f + 2 * IN_DIM * HC;
    float* asrc_f = Wdst_f + 2 * IN_DIM * HC;
    float* adst_f = asrc_f + 2 * HEADS * HID;
    float* cbias_f= adst_f + 2 * HEADS * HID;
    float* linW_f = cbias_f + 2 * HC;
    float* linb_f = linW_f + 2 * IN_DIM * HC;
    float* gamma_f= linb_f + 2 * HC;
    float* beta_f = gamma_f + 2 * HC;
    float* fcW_f  = beta_f + 2 * HC;
    float* fcb_f  = fcW_f + IN_DIM * NUM_CLASSES;

    // ---- d_out doubles as scratch (all dead before final GEMM writes) ----
    float* acc     = (float*)d_out;                       // N*128 f32 (51.2 MB)
    int*   eids    = (int*)(acc + (size_t)N_NODES * HC);  // 1.6M      (6.4 MB)
    int*   offsets = eids + N_EDGES;                      // N+1       (0.4 MB)
    int*   cursor  = offsets + N_NODES + 1;               // N         (0.4 MB)
    // total 58.4 MB <= 69.8 MB (bf16 out) — fits either dtype

    detect_dtype<<<1, 64, 0, stream>>>((const uint32_t*)x_in, flag);

    // convert all float params (+x) to canonical fp32
    cvt_f32<<<1024, 256, 0, stream>>>(x_in, xf, N_NODES * HC, flag);
    cvt_f32<<<64, 256, 0, stream>>>(d_in[2], Wsrc_f, 2 * IN_DIM * HC, flag);
    cvt_f32<<<64, 256, 0, stream>>>(d_in[3], Wdst_f, 2 * IN_DIM * HC, flag);
    cvt_f32<<<1, 256, 0, stream>>>(d_in[4], asrc_f, 2 * HEADS * HID, flag);
    cvt_f32<<<1, 256, 0, stream>>>(d_in[5], adst_f, 2 * HEADS * HID, flag);
    cvt_f32<<<1, 256, 0, stream>>>(d_in[6], cbias_f, 2 * HC, flag);
    cvt_f32<<<64, 256, 0, stream>>>(d_in[7], linW_f, 2 * IN_DIM * HC, flag);
    cvt_f32<<<1, 256, 0, stream>>>(d_in[8], linb_f, 2 * HC, flag);
    cvt_f32<<<1, 256, 0, stream>>>(d_in[9], gamma_f, 2 * HC, flag);
    cvt_f32<<<1, 256, 0, stream>>>(d_in[10], beta_f, 2 * HC, flag);
    cvt_f32<<<175, 256, 0, stream>>>(d_in[11], fcW_f, IN_DIM * NUM_CLASSES, flag);
    cvt_f32<<<2, 256, 0, stream>>>(d_in[12], fcb_f, NUM_CLASSES, flag);

    // ---- build CSR once (edge list is layer-invariant) ----
    hipMemsetAsync(cursor, 0, N_NODES * sizeof(int), stream);
    hist_dst<<<(N_EDGES + 255) / 256, 256, 0, stream>>>(edst, cursor);
    scan_partial<<<SCAN_BLOCKS, 256, 0, stream>>>(cursor, bsum);
    scan_bsums<<<1, 64, 0, stream>>>(bsum);
    scan_final<<<SCAN_BLOCKS, 256, 0, stream>>>(cursor, bsum, offsets);
    copy_i32<<<(N_NODES + 255) / 256, 256, 0, stream>>>(offsets, cursor, N_NODES);
    scatter_edges<<<(N_EDGES + 255) / 256, 256, 0, stream>>>(edst, cursor, eids);

    for (int layer = 0; layer < NUM_LAYERS; layer++) {
        const int woff = layer * IN_DIM * HC;
        const int aoff = layer * HEADS * HID;
        const int boff = layer * HC;

        build_bcat<<<(IN_DIM * NCAT + 255) / 256, 256, 0, stream>>>(
            Wsrc_f + woff, Wdst_f + woff, asrc_f + aoff, adst_f + aoff,
            linW_f + woff, Bcat);

        dim3 gb((NCAT + 15) / 16, (N_NODES + 15) / 16);
        gemm_proj<<<gb, dim3(16, 16), 0, stream>>>(xf, Bcat, proj,
                                                   N_NODES, NCAT, IN_DIM);

        hipMemsetAsync(bnsum, 0, 256 * sizeof(float), stream);

        gat_gather<<<N_NODES / 4, 256, 0, stream>>>(eids, offsets, esrc, proj, acc);

        post_bn<<<(N_NODES + 127) / 128, 256, 0, stream>>>(
            acc, proj, cbias_f + boff, linb_f + boff, bnsum, bnsq);
        bn_apply<<<(N_NODES * HC + 255) / 256, 256, 0, stream>>>(
            acc, xf, gamma_f + boff, beta_f + boff, bnsum, bnsq);
    }

    dim3 gf((NUM_CLASSES + 15) / 16, (N_NODES + 15) / 16);
    gemm_out<<<gf, dim3(16, 16), 0, stream>>>(xf, fcW_f, fcb_f, d_out,
                                              N_NODES, NUM_CLASSES, IN_DIM, flag);
}

// Round 4
// 1627.484 us; speedup vs baseline: 2.8645x; 1.7963x over previous
//
#include <hip/hip_runtime.h>
#include <hip/hip_bf16.h>
#include <stdint.h>

#define N_NODES 100000
#define N_EDGES 1600000
#define IN_DIM 128
#define HEADS 4
#define HID 32
#define HC 128
#define NUM_CLASSES 349
#define NUM_LAYERS 2
#define BN_EPS 1e-5f
#define NEG_SLOPE 0.2f
#define NCAT 264      // logical: [xs(128) | s_src(4) | s_dst(4) | xlin(128)]
#define PLD 272       // padded proj leading dim (17*16)
#define MP 100032     // N_NODES padded to 64 (1563 blocks)

#define SCAN_CHUNK 1024
#define SCAN_BLOCKS ((N_NODES + SCAN_CHUNK - 1) / SCAN_CHUNK)  // 98

using bf16 = __hip_bfloat16;
typedef __attribute__((ext_vector_type(8))) short short8;
typedef __attribute__((ext_vector_type(4))) float floatx4;

__device__ __forceinline__ float b2f(bf16 v) { return __bfloat162float(v); }

// -------------------------------------------------- runtime dtype detection
__global__ void detect_dtype(const uint32_t* __restrict__ xw, int* __restrict__ flag) {
    if (threadIdx.x != 0 || blockIdx.x != 0) return;
    int insane = 0;
    for (int i = 0; i < 256; i++) {
        uint32_t lo = xw[i] & 0xffffu;
        uint32_t e = (lo >> 7) & 0xffu;
        if (lo != 0u && (e < 100u || e > 150u)) insane++;
    }
    *flag = (insane > 64) ? 1 : 0;
}

// ------------------------------------------- dtype-flexible converts
__global__ void cvt_f32(const void* __restrict__ in, float* __restrict__ out,
                        int n, const int* __restrict__ flag) {
    bool isf32 = (*flag != 0);
    int i = blockIdx.x * blockDim.x + threadIdx.x;
    int stride = gridDim.x * blockDim.x;
    for (; i < n; i += stride)
        out[i] = isf32 ? ((const float*)in)[i] : b2f(((const bf16*)in)[i]);
}

// x -> bf16, zero-pad rows [N_NODES, MP)
__global__ void cvt_xb(const void* __restrict__ in, bf16* __restrict__ out,
                       int n, int npad, const int* __restrict__ flag) {
    bool isf32 = (*flag != 0);
    int i = blockIdx.x * blockDim.x + threadIdx.x;
    int stride = gridDim.x * blockDim.x;
    for (; i < npad; i += stride) {
        bf16 v = __float2bfloat16(0.f);
        if (i < n) v = isf32 ? __float2bfloat16(((const float*)in)[i]) : ((const bf16*)in)[i];
        out[i] = v;
    }
}

// ------------------------------------------------------- build fused B matrix
// Bcat fp32 [128 x 264] = [W_src | wtilde_src | wtilde_dst | lin_W]
__global__ void build_bcat(const float* __restrict__ Wsrc, const float* __restrict__ Wdst,
                           const float* __restrict__ asrc, const float* __restrict__ adst,
                           const float* __restrict__ linW, float* __restrict__ B) {
    int idx = blockIdx.x * blockDim.x + threadIdx.x;
    if (idx >= IN_DIM * NCAT) return;
    int k = idx / NCAT, j = idx - k * NCAT;
    float v;
    if (j < 128) {
        v = Wsrc[k * HC + j];
    } else if (j < 132) {
        int h = j - 128; float s = 0.f;
        for (int c = 0; c < HID; c++) s += Wsrc[k * HC + h * HID + c] * asrc[h * HID + c];
        v = s;
    } else if (j < 136) {
        int h = j - 132; float s = 0.f;
        for (int c = 0; c < HID; c++) s += Wdst[k * HC + h * HID + c] * adst[h * HID + c];
        v = s;
    } else {
        v = linW[k * HC + (j - 136)];
    }
    B[idx] = v;
}

// ------------------------------------ pack K x N fp32 into MFMA B-frag layout
// Bp[((nt*4+kt)*64+lane)*8+j] = B[k=kt*32+(lane>>4)*8+j][n=nt*16+(lane&15)]
__global__ void pack_b(const float* __restrict__ src, int ld, int nvalid,
                       bf16* __restrict__ Bp, int total) {
    int idx = blockIdx.x * blockDim.x + threadIdx.x;
    if (idx >= total) return;
    int j = idx & 7, lane = (idx >> 3) & 63, kt = (idx >> 9) & 3, nt = idx >> 11;
    int n = nt * 16 + (lane & 15);
    int k = kt * 32 + ((lane >> 4) << 3) + j;
    float v = (n < nvalid) ? src[k * ld + n] : 0.f;
    Bp[idx] = __float2bfloat16(v);
}

// ================================ MFMA GEMMs ================================
// block = 256 thr (4 waves), 64 rows/block, full K=128 staged once in LDS.
__global__ __launch_bounds__(256) void gemm_mfma_proj(
    const bf16* __restrict__ A,    // MP x 128
    const bf16* __restrict__ Bp,   // packed 17*2048
    bf16* __restrict__ C) {        // MP x 272
    __shared__ bf16 As[64 * 128];
    int tid = threadIdx.x;
    size_t rowbase = (size_t)blockIdx.x * 64;
    const int4* ga = (const int4*)(A + rowbase * 128);
    int4* la = (int4*)As;
#pragma unroll
    for (int s = 0; s < 4; s++) la[s * 256 + tid] = ga[s * 256 + tid];
    __syncthreads();
    int wave = tid >> 6, lane = tid & 63;
    int arow = wave * 16 + (lane & 15);
    int acol = (lane >> 4) * 8;
    short8 afrag[4];
#pragma unroll
    for (int kt = 0; kt < 4; kt++)
        afrag[kt] = *(const short8*)&As[arow * 128 + kt * 32 + acol];
    const short8* bbase = (const short8*)Bp + lane;
    int colb = lane & 15;
    int row0 = wave * 16 + (lane >> 4) * 4;
    bf16* crow = C + rowbase * PLD;
    for (int nt = 0; nt < 17; nt++) {
        floatx4 acc = {0.f, 0.f, 0.f, 0.f};
#pragma unroll
        for (int kt = 0; kt < 4; kt++)
            acc = __builtin_amdgcn_mfma_f32_16x16x32_bf16(afrag[kt], bbase[(nt * 4 + kt) * 64], acc, 0, 0, 0);
        int col = nt * 16 + colb;
#pragma unroll
        for (int r = 0; r < 4; r++)
            crow[(size_t)(row0 + r) * PLD + col] = __float2bfloat16(acc[r]);
    }
}

__global__ __launch_bounds__(256) void gemm_mfma_out(
    const bf16* __restrict__ A,    // MP x 128
    const bf16* __restrict__ Bp,   // packed 22*2048
    const float* __restrict__ bias,
    void* __restrict__ C,          // N_NODES x 349
    const int* __restrict__ flag) {
    __shared__ bf16 As[64 * 128];
    int tid = threadIdx.x;
    size_t rowbase = (size_t)blockIdx.x * 64;
    const int4* ga = (const int4*)(A + rowbase * 128);
    int4* la = (int4*)As;
#pragma unroll
    for (int s = 0; s < 4; s++) la[s * 256 + tid] = ga[s * 256 + tid];
    __syncthreads();
    int wave = tid >> 6, lane = tid & 63;
    int arow = wave * 16 + (lane & 15);
    int acol = (lane >> 4) * 8;
    short8 afrag[4];
#pragma unroll
    for (int kt = 0; kt < 4; kt++)
        afrag[kt] = *(const short8*)&As[arow * 128 + kt * 32 + acol];
    const short8* bbase = (const short8*)Bp + lane;
    int colb = lane & 15;
    int row0 = wave * 16 + (lane >> 4) * 4;
    bool isf32 = (*flag != 0);
    for (int nt = 0; nt < 22; nt++) {
        floatx4 acc = {0.f, 0.f, 0.f, 0.f};
#pragma unroll
        for (int kt = 0; kt < 4; kt++)
            acc = __builtin_amdgcn_mfma_f32_16x16x32_bf16(afrag[kt], bbase[(nt * 4 + kt) * 64], acc, 0, 0, 0);
        int col = nt * 16 + colb;
        if (col >= NUM_CLASSES) continue;
        float bv = bias[col];
#pragma unroll
        for (int r = 0; r < 4; r++) {
            size_t row = rowbase + row0 + r;
            if (row < N_NODES) {
                float v = acc[r] + bv;
                if (isf32) ((float*)C)[row * NUM_CLASSES + col] = v;
                else       ((bf16*)C)[row * NUM_CLASSES + col] = __float2bfloat16(v);
            }
        }
    }
}

// ================================ CSR build ================================
__global__ void hist_dst(const int* __restrict__ dst, int* __restrict__ counts) {
    int e = blockIdx.x * blockDim.x + threadIdx.x;
    if (e < N_EDGES) atomicAdd(&counts[dst[e]], 1);
}

__global__ void scan_partial(const int* __restrict__ counts, int* __restrict__ bsum) {
    __shared__ int red[256];
    int t = threadIdx.x;
    int base = blockIdx.x * SCAN_CHUNK + t * 4;
    int s = 0;
#pragma unroll
    for (int j = 0; j < 4; j++) {
        int idx = base + j;
        if (idx < N_NODES) s += counts[idx];
    }
    red[t] = s;
    __syncthreads();
    for (int off = 128; off > 0; off >>= 1) {
        if (t < off) red[t] += red[t + off];
        __syncthreads();
    }
    if (t == 0) bsum[blockIdx.x] = red[0];
}

__global__ void scan_bsums(int* __restrict__ bsum) {
    if (threadIdx.x != 0 || blockIdx.x != 0) return;
    int run = 0;
    for (int i = 0; i < SCAN_BLOCKS; i++) {
        int v = bsum[i];
        bsum[i] = run;
        run += v;
    }
}

__global__ void scan_final(const int* __restrict__ counts, const int* __restrict__ bsum,
                           int* __restrict__ offsets) {
    __shared__ int ts[256];
    int t = threadIdx.x;
    int base = blockIdx.x * SCAN_CHUNK + t * 4;
    int c[4];
    int mysum = 0;
#pragma unroll
    for (int j = 0; j < 4; j++) {
        int idx = base + j;
        c[j] = (idx < N_NODES) ? counts[idx] : 0;
        mysum += c[j];
    }
    ts[t] = mysum;
    __syncthreads();
    for (int off = 1; off < 256; off <<= 1) {
        int v = (t >= off) ? ts[t - off] : 0;
        __syncthreads();
        ts[t] += v;
        __syncthreads();
    }
    int run = bsum[blockIdx.x] + ts[t] - mysum;
#pragma unroll
    for (int j = 0; j < 4; j++) {
        int idx = base + j;
        if (idx < N_NODES) {
            offsets[idx] = run;
            run += c[j];
            if (idx == N_NODES - 1) offsets[N_NODES] = run;
        }
    }
}

__global__ void copy_i32(const int* __restrict__ in, int* __restrict__ out, int n) {
    int i = blockIdx.x * blockDim.x + threadIdx.x;
    if (i < n) out[i] = in[i];
}

__global__ void scatter_edges(const int* __restrict__ dst, int* __restrict__ cursor,
                              int* __restrict__ eids) {
    int e = blockIdx.x * blockDim.x + threadIdx.x;
    if (e >= N_EDGES) return;
    int pos = atomicAdd(&cursor[dst[e]], 1);
    eids[pos] = e;
}

// ================================ GAT gather ================================
__global__ void gat_gather(const int* __restrict__ eids,
                           const int* __restrict__ offsets,
                           const int* __restrict__ src,
                           const bf16* __restrict__ proj,
                           float* __restrict__ acc) {
    int n = blockIdx.x * 4 + (threadIdx.x >> 6);
    int lane = threadIdx.x & 63;
    int c0 = lane * 2;
    int h = c0 >> 5;
    int beg = offsets[n], end = offsets[n + 1];
    float s_dst = b2f(proj[(size_t)n * PLD + 132 + h]);
    float denom = 0.f;
    for (int i = beg; i < end; i++) {
        int s = src[eids[i]];
        float sc = b2f(proj[(size_t)s * PLD + 128 + h]) + s_dst;
        sc = sc > 0.f ? sc : NEG_SLOPE * sc;
        denom += __expf(sc);
    }
    float rdenom = 1.f / (denom + 1e-16f);
    float a0 = 0.f, a1 = 0.f;
    for (int i = beg; i < end; i++) {
        int s = src[eids[i]];
        size_t rb = (size_t)s * PLD;
        float sc = b2f(proj[rb + 128 + h]) + s_dst;
        sc = sc > 0.f ? sc : NEG_SLOPE * sc;
        float alpha = __expf(sc) * rdenom;
        __hip_bfloat162 xv = *reinterpret_cast<const __hip_bfloat162*>(&proj[rb + c0]);
        a0 += b2f(xv.x) * alpha;
        a1 += b2f(xv.y) * alpha;
    }
    acc[(size_t)n * HC + c0]     = a0;
    acc[(size_t)n * HC + c0 + 1] = a1;
}

// ------------------------------------------ h = acc + bias + skip; BN partial sums
__global__ void post_bn(float* __restrict__ acc, const bf16* __restrict__ proj,
                        const float* __restrict__ cbias, const float* __restrict__ lbias,
                        float* __restrict__ bnsum, float* __restrict__ bnsq) {
    int c = threadIdx.x & 127;
    int half = threadIdx.x >> 7;
    int r0 = blockIdx.x * 128;
    int rend = r0 + 128; if (rend > N_NODES) rend = N_NODES;
    float bias = cbias[c] + lbias[c];
    float s1 = 0.f, s2 = 0.f;
    for (int r = r0 + half; r < rend; r += 2) {
        float v = acc[r * HC + c] + b2f(proj[(size_t)r * PLD + 136 + c]) + bias;
        acc[r * HC + c] = v;
        s1 += v; s2 += v * v;
    }
    atomicAdd(&bnsum[c], s1);
    atomicAdd(&bnsq[c], s2);
}

// ------------------------------------------------------- BN normalize + ReLU -> bf16 x
__global__ void bn_apply(const float* __restrict__ h, bf16* __restrict__ xout,
                         const float* __restrict__ gamma, const float* __restrict__ beta,
                         const float* __restrict__ bnsum, const float* __restrict__ bnsq) {
    int idx = blockIdx.x * blockDim.x + threadIdx.x;
    if (idx >= N_NODES * HC) return;
    int c = idx & 127;
    const float invN = 1.f / (float)N_NODES;
    float mu = bnsum[c] * invN;
    float var = bnsq[c] * invN - mu * mu;
    float v = gamma[c] * (h[idx] - mu) * rsqrtf(var + BN_EPS) + beta[c];
    xout[idx] = __float2bfloat16(v > 0.f ? v : 0.f);
}

// ==========================================================================
extern "C" void kernel_launch(void* const* d_in, const int* in_sizes, int n_in,
                              void* d_out, int out_size, void* d_ws, size_t ws_size,
                              hipStream_t stream) {
    const void* x_in  = d_in[0];
    const int*  edge  = (const int*)d_in[1];
    const int* esrc = edge;
    const int* edst = edge + N_EDGES;

    // ---- d_ws layout ----
    bf16* xb   = (bf16*)d_ws;                              // MP*128 bf16 (25.6 MB)
    bf16* proj = xb + (size_t)MP * HC;                     // MP*272 bf16 (54.4 MB)
    float* Bcat = (float*)(proj + (size_t)MP * PLD);       // 128*264 f32
    bf16* Bp   = (bf16*)(Bcat + IN_DIM * NCAT);            // 17*2048 bf16
    bf16* fcWp = Bp + 17 * 2048;                           // 22*2048 bf16
    float* fptr = (float*)(fcWp + 22 * 2048);
    float* bnsum = fptr;                                   // 128
    float* bnsq  = bnsum + 128;                            // 128
    int*   flag  = (int*)(bnsq + 128);                     // 1 (+pad)
    int*   bsum  = flag + 4;                               // 98
    float* parms = (float*)(bsum + SCAN_BLOCKS + 2);
    float* Wsrc_f = parms;                        // 2*128*128
    float* Wdst_f = Wsrc_f + 2 * IN_DIM * HC;
    float* asrc_f = Wdst_f + 2 * IN_DIM * HC;
    float* adst_f = asrc_f + 2 * HEADS * HID;
    float* cbias_f= adst_f + 2 * HEADS * HID;
    float* linW_f = cbias_f + 2 * HC;
    float* linb_f = linW_f + 2 * IN_DIM * HC;
    float* gamma_f= linb_f + 2 * HC;
    float* beta_f = gamma_f + 2 * HC;
    float* fcW_f  = beta_f + 2 * HC;              // 128*349
    float* fcb_f  = fcW_f + IN_DIM * NUM_CLASSES; // 349

    // ---- d_out doubles as scratch (dead before final GEMM writes) ----
    float* acc     = (float*)d_out;                        // N*128 f32 (51.2 MB)
    int*   eids    = (int*)(acc + (size_t)N_NODES * HC);   // 6.4 MB
    int*   offsets = eids + N_EDGES;                       // 0.4 MB
    int*   cursor  = offsets + N_NODES + 1;                // 0.4 MB

    detect_dtype<<<1, 64, 0, stream>>>((const uint32_t*)x_in, flag);

    cvt_xb<<<1024, 256, 0, stream>>>(x_in, xb, N_NODES * HC, MP * HC, flag);
    cvt_f32<<<64, 256, 0, stream>>>(d_in[2], Wsrc_f, 2 * IN_DIM * HC, flag);
    cvt_f32<<<64, 256, 0, stream>>>(d_in[3], Wdst_f, 2 * IN_DIM * HC, flag);
    cvt_f32<<<1, 256, 0, stream>>>(d_in[4], asrc_f, 2 * HEADS * HID, flag);
    cvt_f32<<<1, 256, 0, stream>>>(d_in[5], adst_f, 2 * HEADS * HID, flag);
    cvt_f32<<<1, 256, 0, stream>>>(d_in[6], cbias_f, 2 * HC, flag);
    cvt_f32<<<64, 256, 0, stream>>>(d_in[7], linW_f, 2 * IN_DIM * HC, flag);
    cvt_f32<<<1, 256, 0, stream>>>(d_in[8], linb_f, 2 * HC, flag);
    cvt_f32<<<1, 256, 0, stream>>>(d_in[9], gamma_f, 2 * HC, flag);
    cvt_f32<<<1, 256, 0, stream>>>(d_in[10], beta_f, 2 * HC, flag);
    cvt_f32<<<175, 256, 0, stream>>>(d_in[11], fcW_f, IN_DIM * NUM_CLASSES, flag);
    cvt_f32<<<2, 256, 0, stream>>>(d_in[12], fcb_f, NUM_CLASSES, flag);

    // ---- build CSR once ----
    hipMemsetAsync(cursor, 0, N_NODES * sizeof(int), stream);
    hist_dst<<<(N_EDGES + 255) / 256, 256, 0, stream>>>(edst, cursor);
    scan_partial<<<SCAN_BLOCKS, 256, 0, stream>>>(cursor, bsum);
    scan_bsums<<<1, 64, 0, stream>>>(bsum);
    scan_final<<<SCAN_BLOCKS, 256, 0, stream>>>(cursor, bsum, offsets);
    copy_i32<<<(N_NODES + 255) / 256, 256, 0, stream>>>(offsets, cursor, N_NODES);
    scatter_edges<<<(N_EDGES + 255) / 256, 256, 0, stream>>>(edst, cursor, eids);

    // ---- pack fc weights once ----
    pack_b<<<(22 * 2048 + 255) / 256, 256, 0, stream>>>(fcW_f, NUM_CLASSES, NUM_CLASSES,
                                                        fcWp, 22 * 2048);

    for (int layer = 0; layer < NUM_LAYERS; layer++) {
        const int woff = layer * IN_DIM * HC;
        const int aoff = layer * HEADS * HID;
        const int boff = layer * HC;

        build_bcat<<<(IN_DIM * NCAT + 255) / 256, 256, 0, stream>>>(
            Wsrc_f + woff, Wdst_f + woff, asrc_f + aoff, adst_f + aoff,
            linW_f + woff, Bcat);
        pack_b<<<(17 * 2048 + 255) / 256, 256, 0, stream>>>(Bcat, NCAT, NCAT,
                                                            Bp, 17 * 2048);

        gemm_mfma_proj<<<MP / 64, 256, 0, stream>>>(xb, Bp, proj);

        hipMemsetAsync(bnsum, 0, 256 * sizeof(float), stream);

        gat_gather<<<N_NODES / 4, 256, 0, stream>>>(eids, offsets, esrc, proj, acc);

        post_bn<<<(N_NODES + 127) / 128, 256, 0, stream>>>(
            acc, proj, cbias_f + boff, linb_f + boff, bnsum, bnsq);
        bn_apply<<<(N_NODES * HC + 255) / 256, 256, 0, stream>>>(
            acc, xb, gamma_f + boff, beta_f + boff, bnsum, bnsq);
    }

    gemm_mfma_out<<<MP / 64, 256, 0, stream>>>(xb, fcWp, fcb_f, d_out, flag);
}

// Round 5
// 918.489 us; speedup vs baseline: 5.0757x; 1.7719x over previous
//
#include <hip/hip_runtime.h>
#include <hip/hip_bf16.h>
#include <stdint.h>

#define N_NODES 100000
#define N_EDGES 1600000
#define IN_DIM 128
#define HEADS 4
#define HID 32
#define HC 128
#define NUM_CLASSES 349
#define NUM_LAYERS 2
#define BN_EPS 1e-5f
#define NEG_SLOPE 0.2f
#define NCAT 264      // logical: [xs(128) | s_src(4) | s_dst(4) | xlin(128)]
#define MP 100032     // N_NODES padded to 64 (1563 blocks)

#define SCAN_CHUNK 1024
#define SCAN_BLOCKS ((N_NODES + SCAN_CHUNK - 1) / SCAN_CHUNK)  // 98

using bf16 = __hip_bfloat16;
typedef __attribute__((ext_vector_type(8))) short short8;
typedef __attribute__((ext_vector_type(4))) float floatx4;

__device__ __forceinline__ float b2f(bf16 v) { return __bfloat162float(v); }

// -------------------------------------------------- runtime dtype detection
__global__ void detect_dtype(const uint32_t* __restrict__ xw, int* __restrict__ flag) {
    if (threadIdx.x != 0 || blockIdx.x != 0) return;
    int insane = 0;
    for (int i = 0; i < 256; i++) {
        uint32_t lo = xw[i] & 0xffffu;
        uint32_t e = (lo >> 7) & 0xffu;
        if (lo != 0u && (e < 100u || e > 150u)) insane++;
    }
    *flag = (insane > 64) ? 1 : 0;
}

// ------------------------------------------- dtype-flexible converts
__global__ void cvt_f32(const void* __restrict__ in, float* __restrict__ out,
                        int n, const int* __restrict__ flag) {
    bool isf32 = (*flag != 0);
    int i = blockIdx.x * blockDim.x + threadIdx.x;
    int stride = gridDim.x * blockDim.x;
    for (; i < n; i += stride)
        out[i] = isf32 ? ((const float*)in)[i] : b2f(((const bf16*)in)[i]);
}

// x -> bf16, zero-pad rows [N_NODES, MP)
__global__ void cvt_xb(const void* __restrict__ in, bf16* __restrict__ out,
                       int n, int npad, const int* __restrict__ flag) {
    bool isf32 = (*flag != 0);
    int i = blockIdx.x * blockDim.x + threadIdx.x;
    int stride = gridDim.x * blockDim.x;
    for (; i < npad; i += stride) {
        bf16 v = __float2bfloat16(0.f);
        if (i < n) v = isf32 ? __float2bfloat16(((const float*)in)[i]) : ((const bf16*)in)[i];
        out[i] = v;
    }
}

// ------------------------------------------------------- build fused B matrix
// Bcat fp32 [128 x 264] = [W_src | wtilde_src | wtilde_dst | lin_W]
__global__ void build_bcat(const float* __restrict__ Wsrc, const float* __restrict__ Wdst,
                           const float* __restrict__ asrc, const float* __restrict__ adst,
                           const float* __restrict__ linW, float* __restrict__ B) {
    int idx = blockIdx.x * blockDim.x + threadIdx.x;
    if (idx >= IN_DIM * NCAT) return;
    int k = idx / NCAT, j = idx - k * NCAT;
    float v;
    if (j < 128) {
        v = Wsrc[k * HC + j];
    } else if (j < 132) {
        int h = j - 128; float s = 0.f;
        for (int c = 0; c < HID; c++) s += Wsrc[k * HC + h * HID + c] * asrc[h * HID + c];
        v = s;
    } else if (j < 136) {
        int h = j - 132; float s = 0.f;
        for (int c = 0; c < HID; c++) s += Wdst[k * HC + h * HID + c] * adst[h * HID + c];
        v = s;
    } else {
        v = linW[k * HC + (j - 136)];
    }
    B[idx] = v;
}

// ------------------------------------ pack K x N fp32 into MFMA B-frag layout
// Bp[((nt*4+kt)*64+lane)*8+j] = B[k=kt*32+(lane>>4)*8+j][n=nt*16+(lane&15)]
__global__ void pack_b(const float* __restrict__ src, int ld, int nvalid,
                       bf16* __restrict__ Bp, int total) {
    int idx = blockIdx.x * blockDim.x + threadIdx.x;
    if (idx >= total) return;
    int j = idx & 7, lane = (idx >> 3) & 63, kt = (idx >> 9) & 3, nt = idx >> 11;
    int n = nt * 16 + (lane & 15);
    int k = kt * 32 + ((lane >> 4) << 3) + j;
    float v = (n < nvalid) ? src[k * ld + n] : 0.f;
    Bp[idx] = __float2bfloat16(v);
}

// ================================ MFMA GEMMs ================================
// proj GEMM: writes xs [MP x 128], scA [MP x 8], xlin [MP x 128]
__global__ __launch_bounds__(256) void gemm_mfma_proj(
    const bf16* __restrict__ A,    // MP x 128
    const bf16* __restrict__ Bp,   // packed 17*2048
    bf16* __restrict__ xs, bf16* __restrict__ scA, bf16* __restrict__ xlin) {
    __shared__ bf16 As[64 * 128];
    int tid = threadIdx.x;
    size_t rowbase = (size_t)blockIdx.x * 64;
    const int4* ga = (const int4*)(A + rowbase * 128);
    int4* la = (int4*)As;
#pragma unroll
    for (int s = 0; s < 4; s++) la[s * 256 + tid] = ga[s * 256 + tid];
    __syncthreads();
    int wave = tid >> 6, lane = tid & 63;
    int arow = wave * 16 + (lane & 15);
    int acol = (lane >> 4) * 8;
    short8 afrag[4];
#pragma unroll
    for (int kt = 0; kt < 4; kt++)
        afrag[kt] = *(const short8*)&As[arow * 128 + kt * 32 + acol];
    const short8* bbase = (const short8*)Bp + lane;
    int colb = lane & 15;
    int row0 = wave * 16 + (lane >> 4) * 4;
#pragma unroll
    for (int nt = 0; nt < 17; nt++) {
        floatx4 acc = {0.f, 0.f, 0.f, 0.f};
#pragma unroll
        for (int kt = 0; kt < 4; kt++)
            acc = __builtin_amdgcn_mfma_f32_16x16x32_bf16(afrag[kt], bbase[(nt * 4 + kt) * 64], acc, 0, 0, 0);
        int col = nt * 16 + colb;
#pragma unroll
        for (int r = 0; r < 4; r++) {
            size_t row = rowbase + row0 + r;
            bf16 v = __float2bfloat16(acc[r]);
            if (col < 128)       xs[row * HC + col] = v;
            else if (col < 136)  scA[row * 8 + (col - 128)] = v;
            else { int q = col - 136; if (q < 128) xlin[row * HC + q] = v; }
        }
    }
}

__global__ __launch_bounds__(256) void gemm_mfma_out(
    const bf16* __restrict__ A,    // MP x 128
    const bf16* __restrict__ Bp,   // packed 22*2048
    const float* __restrict__ bias,
    void* __restrict__ C,          // N_NODES x 349
    const int* __restrict__ flag) {
    __shared__ bf16 As[64 * 128];
    int tid = threadIdx.x;
    size_t rowbase = (size_t)blockIdx.x * 64;
    const int4* ga = (const int4*)(A + rowbase * 128);
    int4* la = (int4*)As;
#pragma unroll
    for (int s = 0; s < 4; s++) la[s * 256 + tid] = ga[s * 256 + tid];
    __syncthreads();
    int wave = tid >> 6, lane = tid & 63;
    int arow = wave * 16 + (lane & 15);
    int acol = (lane >> 4) * 8;
    short8 afrag[4];
#pragma unroll
    for (int kt = 0; kt < 4; kt++)
        afrag[kt] = *(const short8*)&As[arow * 128 + kt * 32 + acol];
    const short8* bbase = (const short8*)Bp + lane;
    int colb = lane & 15;
    int row0 = wave * 16 + (lane >> 4) * 4;
    bool isf32 = (*flag != 0);
    for (int nt = 0; nt < 22; nt++) {
        floatx4 acc = {0.f, 0.f, 0.f, 0.f};
#pragma unroll
        for (int kt = 0; kt < 4; kt++)
            acc = __builtin_amdgcn_mfma_f32_16x16x32_bf16(afrag[kt], bbase[(nt * 4 + kt) * 64], acc, 0, 0, 0);
        int col = nt * 16 + colb;
        if (col >= NUM_CLASSES) continue;
        float bv = bias[col];
#pragma unroll
        for (int r = 0; r < 4; r++) {
            size_t row = rowbase + row0 + r;
            if (row < N_NODES) {
                float v = acc[r] + bv;
                if (isf32) ((float*)C)[row * NUM_CLASSES + col] = v;
                else       ((bf16*)C)[row * NUM_CLASSES + col] = __float2bfloat16(v);
            }
        }
    }
}

// ================================ CSR build ================================
__global__ void hist_dst(const int* __restrict__ dst, int* __restrict__ counts) {
    int e = blockIdx.x * blockDim.x + threadIdx.x;
    if (e < N_EDGES) atomicAdd(&counts[dst[e]], 1);
}

__global__ void scan_partial(const int* __restrict__ counts, int* __restrict__ bsum) {
    __shared__ int red[256];
    int t = threadIdx.x;
    int base = blockIdx.x * SCAN_CHUNK + t * 4;
    int s = 0;
#pragma unroll
    for (int j = 0; j < 4; j++) {
        int idx = base + j;
        if (idx < N_NODES) s += counts[idx];
    }
    red[t] = s;
    __syncthreads();
    for (int off = 128; off > 0; off >>= 1) {
        if (t < off) red[t] += red[t + off];
        __syncthreads();
    }
    if (t == 0) bsum[blockIdx.x] = red[0];
}

__global__ void scan_bsums(int* __restrict__ bsum) {
    if (threadIdx.x != 0 || blockIdx.x != 0) return;
    int run = 0;
    for (int i = 0; i < SCAN_BLOCKS; i++) {
        int v = bsum[i];
        bsum[i] = run;
        run += v;
    }
}

__global__ void scan_final(const int* __restrict__ counts, const int* __restrict__ bsum,
                           int* __restrict__ offsets) {
    __shared__ int ts[256];
    int t = threadIdx.x;
    int base = blockIdx.x * SCAN_CHUNK + t * 4;
    int c[4];
    int mysum = 0;
#pragma unroll
    for (int j = 0; j < 4; j++) {
        int idx = base + j;
        c[j] = (idx < N_NODES) ? counts[idx] : 0;
        mysum += c[j];
    }
    ts[t] = mysum;
    __syncthreads();
    for (int off = 1; off < 256; off <<= 1) {
        int v = (t >= off) ? ts[t - off] : 0;
        __syncthreads();
        ts[t] += v;
        __syncthreads();
    }
    int run = bsum[blockIdx.x] + ts[t] - mysum;
#pragma unroll
    for (int j = 0; j < 4; j++) {
        int idx = base + j;
        if (idx < N_NODES) {
            offsets[idx] = run;
            run += c[j];
            if (idx == N_NODES - 1) offsets[N_NODES] = run;
        }
    }
}

__global__ void copy_i32(const int* __restrict__ in, int* __restrict__ out, int n) {
    int i = blockIdx.x * blockDim.x + threadIdx.x;
    if (i < n) out[i] = in[i];
}

__global__ void scatter_edges(const int* __restrict__ dst, int* __restrict__ cursor,
                              int* __restrict__ eids) {
    int e = blockIdx.x * blockDim.x + threadIdx.x;
    if (e >= N_EDGES) return;
    int pos = atomicAdd(&cursor[dst[e]], 1);
    eids[pos] = e;
}

// pre-gather source ids in CSR edge order (removes an indirection per edge)
__global__ void gather_src(const int* __restrict__ eids, const int* __restrict__ src,
                           int* __restrict__ srcs) {
    int i = blockIdx.x * blockDim.x + threadIdx.x;
    if (i < N_EDGES) srcs[i] = src[eids[i]];
}

// ================================ GAT gather ================================
// one wave per destination node; 2 channels per lane; SINGLE pass:
// out = (Σ exp(sc)·x) / (Σ exp(sc))   (softmax is shift-invariant; scores are O(1))
__device__ __forceinline__ void edge_acc(int s, int h, int c0, float s_dst,
                                         const bf16* __restrict__ xs,
                                         const bf16* __restrict__ scA,
                                         float& den, float& n0, float& n1) {
    float sc = b2f(scA[(size_t)s * 8 + h]) + s_dst;
    sc = sc > 0.f ? sc : NEG_SLOPE * sc;
    float e = __expf(sc);
    __hip_bfloat162 xv = *reinterpret_cast<const __hip_bfloat162*>(&xs[(size_t)s * HC + c0]);
    den += e;
    n0 += b2f(xv.x) * e;
    n1 += b2f(xv.y) * e;
}

__global__ __launch_bounds__(256) void gat_gather(
    const int* __restrict__ srcs, const int* __restrict__ offsets,
    const bf16* __restrict__ xs, const bf16* __restrict__ scA,
    float* __restrict__ acc) {
    int n = blockIdx.x * 4 + (threadIdx.x >> 6);
    int lane = threadIdx.x & 63;
    int c0 = lane * 2;
    int h = c0 >> 5;
    int beg = offsets[n], end = offsets[n + 1];
    float s_dst = b2f(scA[(size_t)n * 8 + 4 + h]);
    float den = 0.f, n0 = 0.f, n1 = 0.f;
    int i = beg;
    for (; i + 3 < end; i += 4) {
        int s0 = srcs[i], s1 = srcs[i + 1], s2 = srcs[i + 2], s3 = srcs[i + 3];
        edge_acc(s0, h, c0, s_dst, xs, scA, den, n0, n1);
        edge_acc(s1, h, c0, s_dst, xs, scA, den, n0, n1);
        edge_acc(s2, h, c0, s_dst, xs, scA, den, n0, n1);
        edge_acc(s3, h, c0, s_dst, xs, scA, den, n0, n1);
    }
    for (; i < end; i++)
        edge_acc(srcs[i], h, c0, s_dst, xs, scA, den, n0, n1);
    float r = 1.f / (den + 1e-16f);
    acc[(size_t)n * HC + c0]     = n0 * r;
    acc[(size_t)n * HC + c0 + 1] = n1 * r;
}

// ------------------------------------------ h = acc + bias + skip; BN partial sums
__global__ void post_bn(float* __restrict__ acc, const bf16* __restrict__ xlin,
                        const float* __restrict__ cbias, const float* __restrict__ lbias,
                        float* __restrict__ bnsum, float* __restrict__ bnsq) {
    int c = threadIdx.x & 127;
    int half = threadIdx.x >> 7;
    int r0 = blockIdx.x * 128;
    int rend = r0 + 128; if (rend > N_NODES) rend = N_NODES;
    float bias = cbias[c] + lbias[c];
    float s1 = 0.f, s2 = 0.f;
    for (int r = r0 + half; r < rend; r += 2) {
        float v = acc[(size_t)r * HC + c] + b2f(xlin[(size_t)r * HC + c]) + bias;
        acc[(size_t)r * HC + c] = v;
        s1 += v; s2 += v * v;
    }
    atomicAdd(&bnsum[c], s1);
    atomicAdd(&bnsq[c], s2);
}

// ------------------------------------------------------- BN normalize + ReLU -> bf16 x
__global__ void bn_apply(const float* __restrict__ h, bf16* __restrict__ xout,
                         const float* __restrict__ gamma, const float* __restrict__ beta,
                         const float* __restrict__ bnsum, const float* __restrict__ bnsq) {
    int idx = blockIdx.x * blockDim.x + threadIdx.x;
    if (idx >= N_NODES * HC) return;
    int c = idx & 127;
    const float invN = 1.f / (float)N_NODES;
    float mu = bnsum[c] * invN;
    float var = bnsq[c] * invN - mu * mu;
    float v = gamma[c] * (h[idx] - mu) * rsqrtf(var + BN_EPS) + beta[c];
    xout[idx] = __float2bfloat16(v > 0.f ? v : 0.f);
}

// ==========================================================================
extern "C" void kernel_launch(void* const* d_in, const int* in_sizes, int n_in,
                              void* d_out, int out_size, void* d_ws, size_t ws_size,
                              hipStream_t stream) {
    const void* x_in  = d_in[0];
    const int*  edge  = (const int*)d_in[1];
    const int* esrc = edge;
    const int* edst = edge + N_EDGES;

    // ---- d_ws layout ----
    bf16* xb   = (bf16*)d_ws;                              // MP*128 bf16 (25.6 MB)
    bf16* xs   = xb + (size_t)MP * HC;                     // MP*128 bf16 (25.6 MB)
    bf16* scA  = xs + (size_t)MP * HC;                     // MP*8  bf16  (1.6 MB)
    bf16* xlin = scA + (size_t)MP * 8;                     // MP*128 bf16 (25.6 MB)
    float* Bcat = (float*)(xlin + (size_t)MP * HC);        // 128*264 f32
    bf16* Bp   = (bf16*)(Bcat + IN_DIM * NCAT);            // 17*2048 bf16
    bf16* fcWp = Bp + 17 * 2048;                           // 22*2048 bf16
    float* fptr = (float*)(fcWp + 22 * 2048);
    float* bnsum = fptr;                                   // 128
    float* bnsq  = bnsum + 128;                            // 128
    int*   flag  = (int*)(bnsq + 128);                     // 1 (+pad)
    int*   bsum  = flag + 4;                               // 98
    float* parms = (float*)(bsum + SCAN_BLOCKS + 2);
    float* Wsrc_f = parms;                        // 2*128*128
    float* Wdst_f = Wsrc_f + 2 * IN_DIM * HC;
    float* asrc_f = Wdst_f + 2 * IN_DIM * HC;
    float* adst_f = asrc_f + 2 * HEADS * HID;
    float* cbias_f= adst_f + 2 * HEADS * HID;
    float* linW_f = cbias_f + 2 * HC;
    float* linb_f = linW_f + 2 * IN_DIM * HC;
    float* gamma_f= linb_f + 2 * HC;
    float* beta_f = gamma_f + 2 * HC;
    float* fcW_f  = beta_f + 2 * HC;              // 128*349
    float* fcb_f  = fcW_f + IN_DIM * NUM_CLASSES; // 349

    // ---- d_out doubles as scratch (dead before final GEMM writes) ----
    float* acc     = (float*)d_out;                        // N*128 f32 (51.2 MB)
    int*   eids    = (int*)(acc + (size_t)N_NODES * HC);   // 6.4 MB
    int*   srcs    = eids + N_EDGES;                       // 6.4 MB
    int*   offsets = srcs + N_EDGES;                       // 0.4 MB
    int*   cursor  = offsets + N_NODES + 1;                // 0.4 MB
    // total 64.8 MB <= 69.8 MB (bf16 out)

    detect_dtype<<<1, 64, 0, stream>>>((const uint32_t*)x_in, flag);

    cvt_xb<<<1024, 256, 0, stream>>>(x_in, xb, N_NODES * HC, MP * HC, flag);
    cvt_f32<<<64, 256, 0, stream>>>(d_in[2], Wsrc_f, 2 * IN_DIM * HC, flag);
    cvt_f32<<<64, 256, 0, stream>>>(d_in[3], Wdst_f, 2 * IN_DIM * HC, flag);
    cvt_f32<<<1, 256, 0, stream>>>(d_in[4], asrc_f, 2 * HEADS * HID, flag);
    cvt_f32<<<1, 256, 0, stream>>>(d_in[5], adst_f, 2 * HEADS * HID, flag);
    cvt_f32<<<1, 256, 0, stream>>>(d_in[6], cbias_f, 2 * HC, flag);
    cvt_f32<<<64, 256, 0, stream>>>(d_in[7], linW_f, 2 * IN_DIM * HC, flag);
    cvt_f32<<<1, 256, 0, stream>>>(d_in[8], linb_f, 2 * HC, flag);
    cvt_f32<<<1, 256, 0, stream>>>(d_in[9], gamma_f, 2 * HC, flag);
    cvt_f32<<<1, 256, 0, stream>>>(d_in[10], beta_f, 2 * HC, flag);
    cvt_f32<<<175, 256, 0, stream>>>(d_in[11], fcW_f, IN_DIM * NUM_CLASSES, flag);
    cvt_f32<<<2, 256, 0, stream>>>(d_in[12], fcb_f, NUM_CLASSES, flag);

    // ---- build CSR once (edge list is layer-invariant) ----
    hipMemsetAsync(cursor, 0, N_NODES * sizeof(int), stream);
    hist_dst<<<(N_EDGES + 255) / 256, 256, 0, stream>>>(edst, cursor);
    scan_partial<<<SCAN_BLOCKS, 256, 0, stream>>>(cursor, bsum);
    scan_bsums<<<1, 64, 0, stream>>>(bsum);
    scan_final<<<SCAN_BLOCKS, 256, 0, stream>>>(cursor, bsum, offsets);
    copy_i32<<<(N_NODES + 255) / 256, 256, 0, stream>>>(offsets, cursor, N_NODES);
    scatter_edges<<<(N_EDGES + 255) / 256, 256, 0, stream>>>(edst, cursor, eids);
    gather_src<<<(N_EDGES + 255) / 256, 256, 0, stream>>>(eids, esrc, srcs);

    // ---- pack fc weights once ----
    pack_b<<<(22 * 2048 + 255) / 256, 256, 0, stream>>>(fcW_f, NUM_CLASSES, NUM_CLASSES,
                                                        fcWp, 22 * 2048);

    for (int layer = 0; layer < NUM_LAYERS; layer++) {
        const int woff = layer * IN_DIM * HC;
        const int aoff = layer * HEADS * HID;
        const int boff = layer * HC;

        build_bcat<<<(IN_DIM * NCAT + 255) / 256, 256, 0, stream>>>(
            Wsrc_f + woff, Wdst_f + woff, asrc_f + aoff, adst_f + aoff,
            linW_f + woff, Bcat);
        pack_b<<<(17 * 2048 + 255) / 256, 256, 0, stream>>>(Bcat, NCAT, NCAT,
                                                            Bp, 17 * 2048);

        gemm_mfma_proj<<<MP / 64, 256, 0, stream>>>(xb, Bp, xs, scA, xlin);

        hipMemsetAsync(bnsum, 0, 256 * sizeof(float), stream);

        gat_gather<<<N_NODES / 4, 256, 0, stream>>>(srcs, offsets, xs, scA, acc);

        post_bn<<<(N_NODES + 127) / 128, 256, 0, stream>>>(
            acc, xlin, cbias_f + boff, linb_f + boff, bnsum, bnsq);
        bn_apply<<<(N_NODES * HC + 255) / 256, 256, 0, stream>>>(
            acc, xb, gamma_f + boff, beta_f + boff, bnsum, bnsq);
    }

    gemm_mfma_out<<<MP / 64, 256, 0, stream>>>(xb, fcWp, fcb_f, d_out, flag);
}

// Round 6
// 861.507 us; speedup vs baseline: 5.4114x; 1.0661x over previous
//
#include <hip/hip_runtime.h>
#include <hip/hip_bf16.h>
#include <stdint.h>

#define N_NODES 100000
#define N_EDGES 1600000
#define IN_DIM 128
#define HEADS 4
#define HID 32
#define HC 128
#define NUM_CLASSES 349
#define NUM_LAYERS 2
#define BN_EPS 1e-5f
#define NEG_SLOPE 0.2f
#define NCAT 264      // logical: [xs(128) | s_src(4) | s_dst(4) | xlin(128)]
#define MP 100032     // N_NODES padded to 64 (1563 blocks)

#define SCAN_CHUNK 1024
#define SCAN_BLOCKS ((N_NODES + SCAN_CHUNK - 1) / SCAN_CHUNK)  // 98
#define NPARAM 144861

using bf16 = __hip_bfloat16;
typedef __attribute__((ext_vector_type(8))) short short8;
typedef __attribute__((ext_vector_type(4))) float floatx4;

__device__ __forceinline__ float b2f(bf16 v) { return __bfloat162float(v); }

// -------------------------------------------------- runtime dtype detection
__global__ void detect_dtype(const uint32_t* __restrict__ xw, int* __restrict__ flag) {
    int lane = threadIdx.x;  // 64 threads
    int insane = 0;
    for (int i = lane; i < 256; i += 64) {
        uint32_t lo = xw[i] & 0xffffu;
        uint32_t e = (lo >> 7) & 0xffu;
        if (lo != 0u && (e < 100u || e > 150u)) insane++;
    }
    for (int off = 32; off > 0; off >>= 1) insane += __shfl_down(insane, off, 64);
    if (lane == 0) *flag = (insane > 64) ? 1 : 0;
}

// x -> bf16, zero-pad rows [N_NODES, MP)
__global__ void cvt_xb(const void* __restrict__ in, bf16* __restrict__ out,
                       int n, int npad, const int* __restrict__ flag) {
    bool isf32 = (*flag != 0);
    int i = blockIdx.x * blockDim.x + threadIdx.x;
    int stride = gridDim.x * blockDim.x;
    for (; i < npad; i += stride) {
        bf16 v = __float2bfloat16(0.f);
        if (i < n) v = isf32 ? __float2bfloat16(((const float*)in)[i]) : ((const bf16*)in)[i];
        out[i] = v;
    }
}

// all float params -> one contiguous fp32 block (layout = input order)
__global__ void cvt_params(const void* p0, const void* p1, const void* p2, const void* p3,
                           const void* p4, const void* p5, const void* p6, const void* p7,
                           const void* p8, const void* p9, const void* p10,
                           float* __restrict__ out, const int* __restrict__ flag) {
    int i = blockIdx.x * blockDim.x + threadIdx.x;
    if (i >= NPARAM) return;
    bool isf32 = (*flag != 0);
    const void* p; int off;
    if      (i < 32768)  { p = p0;  off = i; }
    else if (i < 65536)  { p = p1;  off = i - 32768; }
    else if (i < 65792)  { p = p2;  off = i - 65536; }
    else if (i < 66048)  { p = p3;  off = i - 65792; }
    else if (i < 66304)  { p = p4;  off = i - 66048; }
    else if (i < 99072)  { p = p5;  off = i - 66304; }
    else if (i < 99328)  { p = p6;  off = i - 99072; }
    else if (i < 99584)  { p = p7;  off = i - 99328; }
    else if (i < 99840)  { p = p8;  off = i - 99584; }
    else if (i < 144512) { p = p9;  off = i - 99840; }
    else                 { p = p10; off = i - 144512; }
    out[i] = isf32 ? ((const float*)p)[off] : b2f(((const bf16*)p)[off]);
}

// ------------------------------------------------------- build fused B matrix
__global__ void build_bcat(const float* __restrict__ Wsrc, const float* __restrict__ Wdst,
                           const float* __restrict__ asrc, const float* __restrict__ adst,
                           const float* __restrict__ linW, float* __restrict__ B) {
    int idx = blockIdx.x * blockDim.x + threadIdx.x;
    if (idx >= IN_DIM * NCAT) return;
    int k = idx / NCAT, j = idx - k * NCAT;
    float v;
    if (j < 128) {
        v = Wsrc[k * HC + j];
    } else if (j < 132) {
        int h = j - 128; float s = 0.f;
        for (int c = 0; c < HID; c++) s += Wsrc[k * HC + h * HID + c] * asrc[h * HID + c];
        v = s;
    } else if (j < 136) {
        int h = j - 132; float s = 0.f;
        for (int c = 0; c < HID; c++) s += Wdst[k * HC + h * HID + c] * adst[h * HID + c];
        v = s;
    } else {
        v = linW[k * HC + (j - 136)];
    }
    B[idx] = v;
}

// ------------------------------------ pack K x N fp32 into MFMA B-frag layout
__global__ void pack_b(const float* __restrict__ src, int ld, int nvalid,
                       bf16* __restrict__ Bp, int total) {
    int idx = blockIdx.x * blockDim.x + threadIdx.x;
    if (idx >= total) return;
    int j = idx & 7, lane = (idx >> 3) & 63, kt = (idx >> 9) & 3, nt = idx >> 11;
    int n = nt * 16 + (lane & 15);
    int k = kt * 32 + ((lane >> 4) << 3) + j;
    float v = (n < nvalid) ? src[k * ld + n] : 0.f;
    Bp[idx] = __float2bfloat16(v);
}

// ================================ MFMA GEMMs ================================
// BNMODE=1: A holds raw h; BN-normalize+ReLU applied during LDS staging.
template <int BNMODE>
__global__ __launch_bounds__(256) void gemm_mfma_proj(
    const bf16* __restrict__ A, const bf16* __restrict__ Bp,
    bf16* __restrict__ xs, bf16* __restrict__ scA, bf16* __restrict__ xlin,
    const float* __restrict__ gamma, const float* __restrict__ beta,
    const float* __restrict__ bnsum, const float* __restrict__ bnsq) {
    __shared__ bf16 As[64 * 128];
    int tid = threadIdx.x;
    size_t rowbase = (size_t)blockIdx.x * 64;
    const int4* ga = (const int4*)(A + rowbase * 128);
    int4* la = (int4*)As;
    const float invN = 1.f / (float)N_NODES;
#pragma unroll
    for (int s = 0; s < 4; s++) {
        int4 raw = ga[s * 256 + tid];
        if (BNMODE) {
            bf16* hv = (bf16*)&raw;
            int cbase = ((s * 256 + tid) & 15) * 8;
            int4 outv; bf16* ov = (bf16*)&outv;
#pragma unroll
            for (int j = 0; j < 8; j++) {
                int c = cbase + j;
                float mu = bnsum[c] * invN;
                float var = bnsq[c] * invN - mu * mu;
                float v = gamma[c] * (b2f(hv[j]) - mu) * rsqrtf(var + BN_EPS) + beta[c];
                ov[j] = __float2bfloat16(v > 0.f ? v : 0.f);
            }
            la[s * 256 + tid] = outv;
        } else {
            la[s * 256 + tid] = raw;
        }
    }
    __syncthreads();
    int wave = tid >> 6, lane = tid & 63;
    int arow = wave * 16 + (lane & 15);
    int acol = (lane >> 4) * 8;
    short8 afrag[4];
#pragma unroll
    for (int kt = 0; kt < 4; kt++)
        afrag[kt] = *(const short8*)&As[arow * 128 + kt * 32 + acol];
    const short8* bbase = (const short8*)Bp + lane;
    int colb = lane & 15;
    int row0 = wave * 16 + (lane >> 4) * 4;
#pragma unroll
    for (int nt = 0; nt < 17; nt++) {
        floatx4 acc = {0.f, 0.f, 0.f, 0.f};
#pragma unroll
        for (int kt = 0; kt < 4; kt++)
            acc = __builtin_amdgcn_mfma_f32_16x16x32_bf16(afrag[kt], bbase[(nt * 4 + kt) * 64], acc, 0, 0, 0);
        int col = nt * 16 + colb;
#pragma unroll
        for (int r = 0; r < 4; r++) {
            size_t row = rowbase + row0 + r;
            bf16 v = __float2bfloat16(acc[r]);
            if (col < 128)       xs[row * HC + col] = v;
            else if (col < 136)  scA[row * 8 + (col - 128)] = v;
            else { int q = col - 136; if (q < 128) xlin[row * HC + q] = v; }
        }
    }
}

// final GEMM: BN+ReLU prologue on h, +bias, dtype-flag store
__global__ __launch_bounds__(256) void gemm_mfma_out(
    const bf16* __restrict__ A, const bf16* __restrict__ Bp,
    const float* __restrict__ bias,
    const float* __restrict__ gamma, const float* __restrict__ beta,
    const float* __restrict__ bnsum, const float* __restrict__ bnsq,
    void* __restrict__ C, const int* __restrict__ flag) {
    __shared__ bf16 As[64 * 128];
    int tid = threadIdx.x;
    size_t rowbase = (size_t)blockIdx.x * 64;
    const int4* ga = (const int4*)(A + rowbase * 128);
    int4* la = (int4*)As;
    const float invN = 1.f / (float)N_NODES;
#pragma unroll
    for (int s = 0; s < 4; s++) {
        int4 raw = ga[s * 256 + tid];
        bf16* hv = (bf16*)&raw;
        int cbase = ((s * 256 + tid) & 15) * 8;
        int4 outv; bf16* ov = (bf16*)&outv;
#pragma unroll
        for (int j = 0; j < 8; j++) {
            int c = cbase + j;
            float mu = bnsum[c] * invN;
            float var = bnsq[c] * invN - mu * mu;
            float v = gamma[c] * (b2f(hv[j]) - mu) * rsqrtf(var + BN_EPS) + beta[c];
            ov[j] = __float2bfloat16(v > 0.f ? v : 0.f);
        }
        la[s * 256 + tid] = outv;
    }
    __syncthreads();
    int wave = tid >> 6, lane = tid & 63;
    int arow = wave * 16 + (lane & 15);
    int acol = (lane >> 4) * 8;
    short8 afrag[4];
#pragma unroll
    for (int kt = 0; kt < 4; kt++)
        afrag[kt] = *(const short8*)&As[arow * 128 + kt * 32 + acol];
    const short8* bbase = (const short8*)Bp + lane;
    int colb = lane & 15;
    int row0 = wave * 16 + (lane >> 4) * 4;
    bool isf32 = (*flag != 0);
    for (int nt = 0; nt < 22; nt++) {
        floatx4 acc = {0.f, 0.f, 0.f, 0.f};
#pragma unroll
        for (int kt = 0; kt < 4; kt++)
            acc = __builtin_amdgcn_mfma_f32_16x16x32_bf16(afrag[kt], bbase[(nt * 4 + kt) * 64], acc, 0, 0, 0);
        int col = nt * 16 + colb;
        if (col >= NUM_CLASSES) continue;
        float bv = bias[col];
#pragma unroll
        for (int r = 0; r < 4; r++) {
            size_t row = rowbase + row0 + r;
            if (row < N_NODES) {
                float v = acc[r] + bv;
                if (isf32) ((float*)C)[row * NUM_CLASSES + col] = v;
                else       ((bf16*)C)[row * NUM_CLASSES + col] = __float2bfloat16(v);
            }
        }
    }
}

// ================================ CSR build ================================
__global__ void hist_dst(const int* __restrict__ dst, int* __restrict__ counts) {
    int e = blockIdx.x * blockDim.x + threadIdx.x;
    if (e < N_EDGES) atomicAdd(&counts[dst[e]], 1);
}

__global__ void scan_partial(const int* __restrict__ counts, int* __restrict__ bsum) {
    __shared__ int red[256];
    int t = threadIdx.x;
    int base = blockIdx.x * SCAN_CHUNK + t * 4;
    int s = 0;
#pragma unroll
    for (int j = 0; j < 4; j++) {
        int idx = base + j;
        if (idx < N_NODES) s += counts[idx];
    }
    red[t] = s;
    __syncthreads();
    for (int off = 128; off > 0; off >>= 1) {
        if (t < off) red[t] += red[t + off];
        __syncthreads();
    }
    if (t == 0) bsum[blockIdx.x] = red[0];
}

__global__ void scan_bsums(int* __restrict__ bsum) {
    if (threadIdx.x != 0 || blockIdx.x != 0) return;
    int run = 0;
    for (int i = 0; i < SCAN_BLOCKS; i++) {
        int v = bsum[i];
        bsum[i] = run;
        run += v;
    }
}

// in-place: counts -> exclusive-scan offsets (reads precede writes per block)
__global__ void scan_final(int* __restrict__ counts, const int* __restrict__ bsum) {
    __shared__ int ts[256];
    int t = threadIdx.x;
    int base = blockIdx.x * SCAN_CHUNK + t * 4;
    int c[4];
    int mysum = 0;
#pragma unroll
    for (int j = 0; j < 4; j++) {
        int idx = base + j;
        c[j] = (idx < N_NODES) ? counts[idx] : 0;
        mysum += c[j];
    }
    ts[t] = mysum;
    __syncthreads();
    for (int off = 1; off < 256; off <<= 1) {
        int v = (t >= off) ? ts[t - off] : 0;
        __syncthreads();
        ts[t] += v;
        __syncthreads();
    }
    int run = bsum[blockIdx.x] + ts[t] - mysum;
#pragma unroll
    for (int j = 0; j < 4; j++) {
        int idx = base + j;
        if (idx < N_NODES) {
            counts[idx] = run;
            run += c[j];
        }
    }
}

// scatter src ids directly into CSR order; offsets acts as cursor
// (after this kernel offsets[n] == end of segment n)
__global__ void scatter_srcs(const int* __restrict__ src, const int* __restrict__ dst,
                             int* __restrict__ offsets, int* __restrict__ srcs) {
    int e = blockIdx.x * blockDim.x + threadIdx.x;
    if (e >= N_EDGES) return;
    int pos = atomicAdd(&offsets[dst[e]], 1);
    srcs[pos] = src[e];
}

// ================================ GAT gather ================================
// single pass: h[n] = (Σ exp(sc)·xs) / (Σ exp(sc)) + xlin[n] + (cbias+lbias)
__device__ __forceinline__ void edge_acc(int s, int h, int c0, float s_dst,
                                         const bf16* __restrict__ xs,
                                         const bf16* __restrict__ scA,
                                         float& den, float& n0, float& n1) {
    float sc = b2f(scA[(size_t)s * 8 + h]) + s_dst;
    sc = sc > 0.f ? sc : NEG_SLOPE * sc;
    float e = __expf(sc);
    __hip_bfloat162 xv = *reinterpret_cast<const __hip_bfloat162*>(&xs[(size_t)s * HC + c0]);
    den += e;
    n0 += b2f(xv.x) * e;
    n1 += b2f(xv.y) * e;
}

__global__ __launch_bounds__(256) void gat_gather(
    const int* __restrict__ srcs, const int* __restrict__ offsets,
    const bf16* __restrict__ xs, const bf16* __restrict__ scA,
    const bf16* __restrict__ xlin,
    const float* __restrict__ cbias, const float* __restrict__ lbias,
    bf16* __restrict__ hout) {
    int n = blockIdx.x * 4 + (threadIdx.x >> 6);
    int lane = threadIdx.x & 63;
    int c0 = lane * 2;
    int h = c0 >> 5;
    int beg = (n == 0) ? 0 : offsets[n - 1];
    int end = offsets[n];
    float s_dst = b2f(scA[(size_t)n * 8 + 4 + h]);
    float den = 0.f, n0 = 0.f, n1 = 0.f;
    int i = beg;
    for (; i + 3 < end; i += 4) {
        int s0 = srcs[i], s1 = srcs[i + 1], s2 = srcs[i + 2], s3 = srcs[i + 3];
        edge_acc(s0, h, c0, s_dst, xs, scA, den, n0, n1);
        edge_acc(s1, h, c0, s_dst, xs, scA, den, n0, n1);
        edge_acc(s2, h, c0, s_dst, xs, scA, den, n0, n1);
        edge_acc(s3, h, c0, s_dst, xs, scA, den, n0, n1);
    }
    for (; i < end; i++)
        edge_acc(srcs[i], h, c0, s_dst, xs, scA, den, n0, n1);
    float r = 1.f / (den + 1e-16f);
    __hip_bfloat162 xl = *reinterpret_cast<const __hip_bfloat162*>(&xlin[(size_t)n * HC + c0]);
    float v0 = n0 * r + b2f(xl.x) + cbias[c0] + lbias[c0];
    float v1 = n1 * r + b2f(xl.y) + cbias[c0 + 1] + lbias[c0 + 1];
    __hip_bfloat162 hv;
    hv.x = __float2bfloat16(v0);
    hv.y = __float2bfloat16(v1);
    *reinterpret_cast<__hip_bfloat162*>(&hout[(size_t)n * HC + c0]) = hv;
}

// ------------------------------------------------------- BN stats (read-only)
__global__ void bn_stats(const bf16* __restrict__ h, float* __restrict__ bnsum,
                         float* __restrict__ bnsq) {
    int c = threadIdx.x & 127;
    int half = threadIdx.x >> 7;
    int r0 = blockIdx.x * 500;
    int rend = r0 + 500; if (rend > N_NODES) rend = N_NODES;
    float s1 = 0.f, s2 = 0.f;
    for (int r = r0 + half; r < rend; r += 2) {
        float v = b2f(h[(size_t)r * HC + c]);
        s1 += v; s2 += v * v;
    }
    atomicAdd(&bnsum[c], s1);
    atomicAdd(&bnsq[c], s2);
}

// ==========================================================================
extern "C" void kernel_launch(void* const* d_in, const int* in_sizes, int n_in,
                              void* d_out, int out_size, void* d_ws, size_t ws_size,
                              hipStream_t stream) {
    const void* x_in = d_in[0];
    const int*  edge = (const int*)d_in[1];
    const int* esrc = edge;
    const int* edst = edge + N_EDGES;

    // ---- d_ws layout ----
    bf16* xbh  = (bf16*)d_ws;                              // MP*128 bf16 (xb, then h)
    bf16* xs   = xbh + (size_t)MP * HC;                    // MP*128 bf16
    bf16* scA  = xs + (size_t)MP * HC;                     // MP*8  bf16
    bf16* xlin = scA + (size_t)MP * 8;                     // MP*128 bf16
    float* Bcat = (float*)(xlin + (size_t)MP * HC);        // 128*264 f32
    bf16* Bp   = (bf16*)(Bcat + IN_DIM * NCAT);            // 17*2048 bf16
    bf16* fcWp = Bp + 17 * 2048;                           // 22*2048 bf16
    float* bnstat = (float*)(fcWp + 22 * 2048);            // 4*128 f32 [s0,q0,s1,q1]
    int*   flag  = (int*)(bnstat + 512);                   // 1 (+pad)
    int*   bsum  = flag + 4;                               // 98
    float* parms = (float*)(bsum + SCAN_BLOCKS + 2);       // NPARAM f32
    // param block offsets (input order)
    float* Wsrc_f  = parms;             // 2*16384
    float* Wdst_f  = parms + 32768;
    float* asrc_f  = parms + 65536;
    float* adst_f  = parms + 65792;
    float* cbias_f = parms + 66048;
    float* linW_f  = parms + 66304;
    float* linb_f  = parms + 99072;
    float* gamma_f = parms + 99328;
    float* beta_f  = parms + 99584;
    float* fcW_f   = parms + 99840;     // 128*349
    float* fcb_f   = parms + 144512;    // 349

    // ---- d_out scratch (dead before gemm_mfma_out writes) ----
    int* srcs    = (int*)d_out;                            // 6.4 MB
    int* offsets = srcs + N_EDGES;                         // 0.4 MB (counts->offsets->ends)

    detect_dtype<<<1, 64, 0, stream>>>((const uint32_t*)x_in, flag);

    cvt_xb<<<1024, 256, 0, stream>>>(x_in, xbh, N_NODES * HC, MP * HC, flag);
    cvt_params<<<(NPARAM + 255) / 256, 256, 0, stream>>>(
        d_in[2], d_in[3], d_in[4], d_in[5], d_in[6], d_in[7], d_in[8],
        d_in[9], d_in[10], d_in[11], d_in[12], parms, flag);

    // ---- CSR build (once; edge list is layer-invariant) ----
    hipMemsetAsync(offsets, 0, N_NODES * sizeof(int), stream);
    hist_dst<<<(N_EDGES + 255) / 256, 256, 0, stream>>>(edst, offsets);
    scan_partial<<<SCAN_BLOCKS, 256, 0, stream>>>(offsets, bsum);
    scan_bsums<<<1, 64, 0, stream>>>(bsum);
    scan_final<<<SCAN_BLOCKS, 256, 0, stream>>>(offsets, bsum);
    scatter_srcs<<<(N_EDGES + 255) / 256, 256, 0, stream>>>(esrc, edst, offsets, srcs);

    pack_b<<<(22 * 2048 + 255) / 256, 256, 0, stream>>>(fcW_f, NUM_CLASSES, NUM_CLASSES,
                                                        fcWp, 22 * 2048);
    hipMemsetAsync(bnstat, 0, 512 * sizeof(float), stream);

    for (int layer = 0; layer < NUM_LAYERS; layer++) {
        const int woff = layer * IN_DIM * HC;
        const int aoff = layer * HEADS * HID;
        const int boff = layer * HC;
        float* bns = bnstat + layer * 256;       // sum
        float* bnq = bns + 128;                  // sumsq

        build_bcat<<<(IN_DIM * NCAT + 255) / 256, 256, 0, stream>>>(
            Wsrc_f + woff, Wdst_f + woff, asrc_f + aoff, adst_f + aoff,
            linW_f + woff, Bcat);
        pack_b<<<(17 * 2048 + 255) / 256, 256, 0, stream>>>(Bcat, NCAT, NCAT,
                                                            Bp, 17 * 2048);

        if (layer == 0) {
            gemm_mfma_proj<0><<<MP / 64, 256, 0, stream>>>(
                xbh, Bp, xs, scA, xlin, nullptr, nullptr, nullptr, nullptr);
        } else {
            float* pbns = bnstat + (layer - 1) * 256;
            gemm_mfma_proj<1><<<MP / 64, 256, 0, stream>>>(
                xbh, Bp, xs, scA, xlin,
                gamma_f + (layer - 1) * HC, beta_f + (layer - 1) * HC,
                pbns, pbns + 128);
        }

        // h overwrites the xbh region (stream-ordered; gat_gather reads only xs/scA/xlin)
        gat_gather<<<N_NODES / 4, 256, 0, stream>>>(
            srcs, offsets, xs, scA, xlin, cbias_f + boff, linb_f + boff, xbh);

        bn_stats<<<200, 256, 0, stream>>>(xbh, bns, bnq);
    }

    gemm_mfma_out<<<MP / 64, 256, 0, stream>>>(
        xbh, fcWp, fcb_f, gamma_f + HC, beta_f + HC,
        bnstat + 256, bnstat + 256 + 128, d_out, flag);
}